// Round 1
// baseline (11518.005 us; speedup 1.0000x reference)
//
#include <hip/hip_runtime.h>
#include <math.h>

#define NB      16384
#define ROWS    64
#define NBLK    (NB/ROWS)     // 256 blocks
#define NTHR    256
#define HSTR    260           // padded row stride for [64][256] fp32 buffers
#define XSTR    132           // padded row stride for encoder xt [32][128]
#define BLB_OFF 4224          // 32*132, start of encoder hnew staging in Hb[1]
#define WLD     20            // W-stage row stride (decoder/fc1, KT=16)
#define WLE     12            // W-stage row stride (encoder,     KT=8)

// packed-weights float4 layout in d_ws
#define ENC4_PER_JT 18432
#define DEC4_OFF    73728
#define FC14_OFF    139264
#define TOTAL4      155648    // * 16 B = 2,490,368 bytes needed in ws

__device__ __forceinline__ float dot4(float4 a, float4 b, float acc){
  acc = fmaf(a.x, b.x, acc);
  acc = fmaf(a.y, b.y, acc);
  acc = fmaf(a.z, b.z, acc);
  acc = fmaf(a.w, b.w, acc);
  return acc;
}
__device__ __forceinline__ float sigm(float v){
  v = fminf(fmaxf(v, -30.0f), 30.0f);
  return __fdividef(1.0f, 1.0f + __expf(-v));
}
__device__ __forceinline__ float tanh_f(float v){
  float t = fminf(fmaxf(v, -15.0f), 15.0f);
  float e = __expf(2.0f * t);
  return __fdividef(e - 1.0f, e + 1.0f);
}

// ---- single source of truth for weight-tile element mapping (prep + fallback) ----
__device__ __forceinline__ float4 enc_w_src4(const float* __restrict__ Wih, const float* __restrict__ Whh,
                                             int jt, int kt, int m, int jr, int k){
  int j = jt*64 + jr;
  const float* p;
  if (kt < 16) p = (m < 3) ? &Wih[(m*256 + j)*128 + k] : &Whh[((m-3)*256 + j)*256 + k];
  else         p = &Whh[(m*256 + j)*256 + k];
  return *(const float4*)p;
}
__device__ __forceinline__ float4 dec_w_src4(const float* __restrict__ Wih, const float* __restrict__ Whh,
                                             int jt, int m, int jr, int k){
  int j = jt*64 + jr;
  if (m == 2) return *(const float4*)&Wih[(512 + j)*256 + k];
  if (m == 3) return *(const float4*)&Whh[(512 + j)*256 + k];
  int row = (m == 0) ? j : (256 + j);
  float4 a = *(const float4*)&Wih[row*256 + k];
  float4 b = *(const float4*)&Whh[row*256 + k];
  return make_float4(a.x+b.x, a.y+b.y, a.z+b.z, a.w+b.w);
}

// ---- prep: pack weights into staging order (coalesced float4 stream) ----
__global__ void prep_pack(const float* __restrict__ eWih, const float* __restrict__ eWhh,
                          const float* __restrict__ dWih, const float* __restrict__ dWhh,
                          const float* __restrict__ f1W, float4* __restrict__ dst){
  int p4 = blockIdx.x * 256 + threadIdx.x;
  if (p4 >= TOTAL4) return;
  float4 v;
  if (p4 < DEC4_OFF){
    int jt  = p4 / ENC4_PER_JT;
    int rem = p4 - jt * ENC4_PER_JT;
    int kt, cc;
    if (rem < 12288){ kt = rem / 768; cc = rem - kt*768; }
    else { int r2 = rem - 12288; kt = 16 + r2/384; cc = r2 - (kt-16)*384; }
    int m = cc >> 7, q = cc & 127, jr = q >> 1, kk = (q & 1) << 2;
    v = enc_w_src4(eWih, eWhh, jt, kt, m, jr, kt*8 + kk);
  } else if (p4 < FC14_OFF){
    int d4 = p4 - DEC4_OFF;
    int tile = d4 >> 10, cc = d4 & 1023;
    int jt = tile >> 4, kt = tile & 15;
    int m = cc >> 8, q = cc & 255, jr = q >> 2, kk = (q & 3) << 2;
    v = dec_w_src4(dWih, dWhh, jt, m, jr, kt*16 + kk);
  } else {
    int f4 = p4 - FC14_OFF;
    int kt = f4 >> 10, cc = f4 & 1023;
    int m = cc >> 8, q = cc & 255, jr = q >> 2, kk = (q & 3) << 2;
    v = *(const float4*)&f1W[(m*64 + jr)*256 + kt*16 + kk];
  }
  dst[p4] = v;
}

// ---- fused persistent kernel: embeddings + 9 enc GRU + 32 x (dec GRU + fc1 + fc2) ----
template<bool PACKED>
__global__ __launch_bounds__(NTHR, 1)
void fused_net(const float* __restrict__ x,
               const float* __restrict__ emW, const float* __restrict__ emb_,
               const float* __restrict__ evW, const float* __restrict__ evb,
               const float* __restrict__ eWih, const float* __restrict__ eWhh,
               const float* __restrict__ ebih, const float* __restrict__ ebhh,
               const float* __restrict__ dWih, const float* __restrict__ dWhh,
               const float* __restrict__ dbih, const float* __restrict__ dbhh,
               const float* __restrict__ f1W, const float* __restrict__ f1b,
               const float* __restrict__ f2W, const float* __restrict__ f2b,
               const float4* __restrict__ ws4, float* __restrict__ out)
{
  __shared__ float Hb[2][16640];   // 2 x [64][260] fp32 ping-pong (h / hnew / fc1-out)
  __shared__ float wl[5120];       // weight stage: dec/fc1 [4][64][20], enc [6][64][12]

  const int tid = threadIdx.x;
  const int r0  = blockIdx.x * ROWS;
  const int cg  = tid >> 3;        // 0..31 -> cols {2cg, 2cg+1} of 64-col tile
  const int rg  = tid & 7;         // rows rg + 8*i

  for (int i2 = tid; i2 < 16640; i2 += NTHR) Hb[0][i2] = 0.0f;  // h0 = 0
  __syncthreads();

  // =============== ENCODER (two half-batches of 32 rows) ===============
  #pragma unroll 1
  for (int half = 0; half < 2; ++half){
    #pragma unroll 1
    for (int t = 0; t < 9; ++t){
      { // xt = tanh(emb) -> Hb[1][rr*132 + e]
        int e = tid & 127;
        int rblk = (tid >> 7) * 16;
        const float* Wp = (t < 8) ? (evW + e*6) : (emW + e*6);
        float bb = (t < 8) ? evb[e] : emb_[e];
        float w0 = Wp[0], w1 = Wp[1], w2 = Wp[2], w3 = Wp[3], w4 = Wp[4], w5 = Wp[5];
        int xo = (t < 8) ? (6 + t*6) : 0;
        #pragma unroll 1
        for (int rr = rblk; rr < rblk + 16; ++rr){
          const float* xs = x + (size_t)(r0 + half*32 + rr)*54 + xo;
          float a = bb + xs[0]*w0 + xs[1]*w1 + xs[2]*w2 + xs[3]*w3 + xs[4]*w4 + xs[5]*w5;
          Hb[1][rr*XSTR + e] = tanh_f(a);
        }
      }
      __syncthreads();

      #pragma unroll 1
      for (int jt = 0; jt < 4; ++jt){
        float ar[2][4] = {}, az[2][4] = {}, ain[2][4] = {}, ahn[2][4] = {};
        float4 st[3];

        auto enc_load = [&](int kt){
          int nch = (kt < 16) ? 768 : 384;
          if constexpr (PACKED){
            const float4* s4 = ws4 + jt*ENC4_PER_JT + ((kt<16) ? kt*768 : 12288 + (kt-16)*384);
            #pragma unroll
            for (int u = 0; u < 3; ++u){ int cc = tid + u*256; if (cc < nch) st[u] = s4[cc]; }
          } else {
            #pragma unroll
            for (int u = 0; u < 3; ++u){ int cc = tid + u*256; if (cc < nch){
              int m = cc >> 7, q = cc & 127, jr = q >> 1, kk = (q & 1) << 2;
              st[u] = enc_w_src4(eWih, eWhh, jt, kt, m, jr, kt*8 + kk);
            }}
          }
        };
        auto enc_write = [&](int kt){
          int nch = (kt < 16) ? 768 : 384;
          #pragma unroll
          for (int u = 0; u < 3; ++u){ int cc = tid + u*256; if (cc < nch){
            int m = cc >> 7, q = cc & 127, jr = q >> 1, kk = (q & 1) << 2;
            *(float4*)&wl[(m*64 + jr)*WLE + kk] = st[u];
          }}
        };

        enc_load(0);
        #pragma unroll 1
        for (int kt = 0; kt < 32; ++kt){
          __syncthreads();
          enc_write(kt);
          __syncthreads();
          if (kt < 31) enc_load(kt + 1);   // prefetch hides under compute below
          int k0 = kt * 8;
          if (kt < 16){
            #pragma unroll
            for (int kk = 0; kk < 8; kk += 4){
              float4 wi0[2], wi1[2], wi2[2], wh0[2], wh1[2], wh2[2];
              #pragma unroll
              for (int c = 0; c < 2; ++c){
                int col = 2*cg + c;
                wi0[c] = *(const float4*)&wl[(0*64 + col)*WLE + kk];
                wi1[c] = *(const float4*)&wl[(1*64 + col)*WLE + kk];
                wi2[c] = *(const float4*)&wl[(2*64 + col)*WLE + kk];
                wh0[c] = *(const float4*)&wl[(3*64 + col)*WLE + kk];
                wh1[c] = *(const float4*)&wl[(4*64 + col)*WLE + kk];
                wh2[c] = *(const float4*)&wl[(5*64 + col)*WLE + kk];
              }
              #pragma unroll
              for (int i = 0; i < 4; ++i){
                int rr = rg + 8*i;
                float4 xv = *(const float4*)&Hb[1][rr*XSTR + k0 + kk];
                float4 hv = *(const float4*)&Hb[0][(half*32 + rr)*HSTR + k0 + kk];
                #pragma unroll
                for (int c = 0; c < 2; ++c){
                  ar[c][i]  = dot4(xv, wi0[c], ar[c][i]);
                  ar[c][i]  = dot4(hv, wh0[c], ar[c][i]);
                  az[c][i]  = dot4(xv, wi1[c], az[c][i]);
                  az[c][i]  = dot4(hv, wh1[c], az[c][i]);
                  ain[c][i] = dot4(xv, wi2[c], ain[c][i]);
                  ahn[c][i] = dot4(hv, wh2[c], ahn[c][i]);
                }
              }
            }
          } else {
            #pragma unroll
            for (int kk = 0; kk < 8; kk += 4){
              float4 wh0[2], wh1[2], wh2[2];
              #pragma unroll
              for (int c = 0; c < 2; ++c){
                int col = 2*cg + c;
                wh0[c] = *(const float4*)&wl[(0*64 + col)*WLE + kk];
                wh1[c] = *(const float4*)&wl[(1*64 + col)*WLE + kk];
                wh2[c] = *(const float4*)&wl[(2*64 + col)*WLE + kk];
              }
              #pragma unroll
              for (int i = 0; i < 4; ++i){
                int rr = rg + 8*i;
                float4 hv = *(const float4*)&Hb[0][(half*32 + rr)*HSTR + k0 + kk];
                #pragma unroll
                for (int c = 0; c < 2; ++c){
                  ar[c][i]  = dot4(hv, wh0[c], ar[c][i]);
                  az[c][i]  = dot4(hv, wh1[c], az[c][i]);
                  ahn[c][i] = dot4(hv, wh2[c], ahn[c][i]);
                }
              }
            }
          }
        }
        // combine -> hnew staged in Hb[1][BLB_OFF..]
        #pragma unroll
        for (int c = 0; c < 2; ++c){
          int j = jt*64 + 2*cg + c;
          float br = ebih[j] + ebhh[j];
          float bz = ebih[256 + j] + ebhh[256 + j];
          float bi = ebih[512 + j];
          float bh = ebhh[512 + j];
          #pragma unroll
          for (int i = 0; i < 4; ++i){
            int rr = rg + 8*i;
            float rv = sigm(ar[c][i] + br);
            float zv = sigm(az[c][i] + bz);
            float nv = tanh_f(ain[c][i] + bi + rv*(ahn[c][i] + bh));
            float ho = Hb[0][(half*32 + rr)*HSTR + j];
            Hb[1][BLB_OFF + rr*HSTR + j] = (1.0f - zv)*nv + zv*ho;
          }
        }
      }
      __syncthreads();
      for (int idx = tid; idx < 32*256; idx += NTHR){
        int rr = idx >> 8, j = idx & 255;
        Hb[0][(half*32 + rr)*HSTR + j] = Hb[1][BLB_OFF + rr*HSTR + j];
      }
      __syncthreads();
    }
  }

  // =============== DECODER (dec_in == h; r/z use pre-summed Wih+Whh) ===============
  int cur = 0;
  #pragma unroll 1
  for (int s = 0; s < 32; ++s){
    #pragma unroll 1
    for (int jt = 0; jt < 4; ++jt){
      float ar[2][8] = {}, az[2][8] = {}, ain[2][8] = {}, ahn[2][8] = {};
      float4 st[4];
      auto dec_load = [&](int kt){
        if constexpr (PACKED){
          const float4* s4 = ws4 + DEC4_OFF + (jt*16 + kt)*1024;
          #pragma unroll
          for (int u = 0; u < 4; ++u) st[u] = s4[tid + u*256];
        } else {
          #pragma unroll
          for (int u = 0; u < 4; ++u){
            int cc = tid + u*256;
            int m = cc >> 8, q = cc & 255, jr = q >> 2, kk = (q & 3) << 2;
            st[u] = dec_w_src4(dWih, dWhh, jt, m, jr, kt*16 + kk);
          }
        }
      };
      auto wl_write4 = [&](){
        #pragma unroll
        for (int u = 0; u < 4; ++u){
          int cc = tid + u*256;
          int m = cc >> 8, q = cc & 255, jr = q >> 2, kk = (q & 3) << 2;
          *(float4*)&wl[(m*64 + jr)*WLD + kk] = st[u];
        }
      };
      dec_load(0);
      #pragma unroll 1
      for (int kt = 0; kt < 16; ++kt){
        __syncthreads();
        wl_write4();
        __syncthreads();
        if (kt < 15) dec_load(kt + 1);
        int k0 = kt * 16;
        #pragma unroll
        for (int kk = 0; kk < 16; kk += 4){
          float4 w0[2], w1[2], w2[2], w3[2];
          #pragma unroll
          for (int c = 0; c < 2; ++c){
            int col = 2*cg + c;
            w0[c] = *(const float4*)&wl[(0*64 + col)*WLD + kk];
            w1[c] = *(const float4*)&wl[(1*64 + col)*WLD + kk];
            w2[c] = *(const float4*)&wl[(2*64 + col)*WLD + kk];
            w3[c] = *(const float4*)&wl[(3*64 + col)*WLD + kk];
          }
          #pragma unroll
          for (int i = 0; i < 8; ++i){
            float4 hv = *(const float4*)&Hb[cur][(rg + 8*i)*HSTR + k0 + kk];
            #pragma unroll
            for (int c = 0; c < 2; ++c){
              ar[c][i]  = dot4(hv, w0[c], ar[c][i]);
              az[c][i]  = dot4(hv, w1[c], az[c][i]);
              ain[c][i] = dot4(hv, w2[c], ain[c][i]);
              ahn[c][i] = dot4(hv, w3[c], ahn[c][i]);
            }
          }
        }
      }
      #pragma unroll
      for (int c = 0; c < 2; ++c){
        int j = jt*64 + 2*cg + c;
        float br = dbih[j] + dbhh[j];
        float bz = dbih[256 + j] + dbhh[256 + j];
        float bi = dbih[512 + j];
        float bh = dbhh[512 + j];
        #pragma unroll
        for (int i = 0; i < 8; ++i){
          int rr = rg + 8*i;
          float rv = sigm(ar[c][i] + br);
          float zv = sigm(az[c][i] + bz);
          float nv = tanh_f(ain[c][i] + bi + rv*(ahn[c][i] + bh));
          float ho = Hb[cur][rr*HSTR + j];
          Hb[cur^1][rr*HSTR + j] = (1.0f - zv)*nv + zv*ho;   // hnew -> other buffer
        }
      }
    }

    // FC1: a = relu(hnew @ fc1.T + b) -> Hb[cur] (h_old is dead)
    {
      float ac0[2][8] = {}, ac1[2][8] = {}, ac2[2][8] = {}, ac3[2][8] = {};
      float4 st[4];
      auto fc1_load = [&](int kt){
        if constexpr (PACKED){
          const float4* s4 = ws4 + FC14_OFF + kt*1024;
          #pragma unroll
          for (int u = 0; u < 4; ++u) st[u] = s4[tid + u*256];
        } else {
          #pragma unroll
          for (int u = 0; u < 4; ++u){
            int cc = tid + u*256;
            int m = cc >> 8, q = cc & 255, jr = q >> 2, kk = (q & 3) << 2;
            st[u] = *(const float4*)&f1W[(m*64 + jr)*256 + kt*16 + kk];
          }
        }
      };
      auto wl_write4b = [&](){
        #pragma unroll
        for (int u = 0; u < 4; ++u){
          int cc = tid + u*256;
          int m = cc >> 8, q = cc & 255, jr = q >> 2, kk = (q & 3) << 2;
          *(float4*)&wl[(m*64 + jr)*WLD + kk] = st[u];
        }
      };
      fc1_load(0);
      #pragma unroll 1
      for (int kt = 0; kt < 16; ++kt){
        __syncthreads();
        wl_write4b();
        __syncthreads();
        if (kt < 15) fc1_load(kt + 1);
        int k0 = kt * 16;
        #pragma unroll
        for (int kk = 0; kk < 16; kk += 4){
          float4 w0[2], w1[2], w2[2], w3[2];
          #pragma unroll
          for (int c = 0; c < 2; ++c){
            int col = 2*cg + c;
            w0[c] = *(const float4*)&wl[(0*64 + col)*WLD + kk];
            w1[c] = *(const float4*)&wl[(1*64 + col)*WLD + kk];
            w2[c] = *(const float4*)&wl[(2*64 + col)*WLD + kk];
            w3[c] = *(const float4*)&wl[(3*64 + col)*WLD + kk];
          }
          #pragma unroll
          for (int i = 0; i < 8; ++i){
            float4 hv = *(const float4*)&Hb[cur^1][(rg + 8*i)*HSTR + k0 + kk];
            #pragma unroll
            for (int c = 0; c < 2; ++c){
              ac0[c][i] = dot4(hv, w0[c], ac0[c][i]);
              ac1[c][i] = dot4(hv, w1[c], ac1[c][i]);
              ac2[c][i] = dot4(hv, w2[c], ac2[c][i]);
              ac3[c][i] = dot4(hv, w3[c], ac3[c][i]);
            }
          }
        }
      }
      #pragma unroll
      for (int c = 0; c < 2; ++c){
        int colb = 2*cg + c;
        float b0 = f1b[colb], b1 = f1b[64 + colb], b2 = f1b[128 + colb], b3 = f1b[192 + colb];
        #pragma unroll
        for (int i = 0; i < 8; ++i){
          int rr = rg + 8*i;
          Hb[cur][rr*HSTR + colb]       = fmaxf(ac0[c][i] + b0, 0.0f);
          Hb[cur][rr*HSTR + 64 + colb]  = fmaxf(ac1[c][i] + b1, 0.0f);
          Hb[cur][rr*HSTR + 128 + colb] = fmaxf(ac2[c][i] + b2, 0.0f);
          Hb[cur][rr*HSTR + 192 + colb] = fmaxf(ac3[c][i] + b3, 0.0f);
        }
      }
    }
    __syncthreads();
    // FC2 + output
    if (tid < 128){
      int rr = tid >> 1, o = tid & 1;
      float acc = f2b[o];
      const float4* wp = (const float4*)(f2W + o*256);
      const float4* ap = (const float4*)&Hb[cur][rr*HSTR];
      #pragma unroll 8
      for (int k4 = 0; k4 < 64; ++k4){
        float4 av = ap[k4];
        float4 wv = wp[k4];
        acc += av.x*wv.x + av.y*wv.y + av.z*wv.z + av.w*wv.w;
      }
      out[((size_t)(r0 + rr)*32 + s)*2 + o] = tanh_f(acc);
    }
    __syncthreads();
    cur ^= 1;
  }
}

extern "C" void kernel_launch(void* const* d_in, const int* in_sizes, int n_in,
                              void* d_out, int out_size, void* d_ws, size_t ws_size,
                              hipStream_t stream)
{
  (void)in_sizes; (void)n_in; (void)out_size;
  const float* x    = (const float*)d_in[0];
  const float* emW  = (const float*)d_in[1];
  const float* emb_ = (const float*)d_in[2];
  const float* evW  = (const float*)d_in[3];
  const float* evb  = (const float*)d_in[4];
  const float* eWih = (const float*)d_in[5];
  const float* eWhh = (const float*)d_in[6];
  const float* ebih = (const float*)d_in[7];
  const float* ebhh = (const float*)d_in[8];
  const float* dWih = (const float*)d_in[9];
  const float* dWhh = (const float*)d_in[10];
  const float* dbih = (const float*)d_in[11];
  const float* dbhh = (const float*)d_in[12];
  const float* f1W  = (const float*)d_in[13];
  const float* f1b  = (const float*)d_in[14];
  const float* f2W  = (const float*)d_in[15];
  const float* f2b  = (const float*)d_in[16];
  float* out = (float*)d_out;

  bool packed = (ws_size >= (size_t)TOTAL4 * 16);
  if (packed){
    prep_pack<<<(TOTAL4 + 255)/256, 256, 0, stream>>>(eWih, eWhh, dWih, dWhh, f1W, (float4*)d_ws);
    fused_net<true><<<NBLK, NTHR, 0, stream>>>(x, emW, emb_, evW, evb, eWih, eWhh, ebih, ebhh,
                                               dWih, dWhh, dbih, dbhh, f1W, f1b, f2W, f2b,
                                               (const float4*)d_ws, out);
  } else {
    fused_net<false><<<NBLK, NTHR, 0, stream>>>(x, emW, emb_, evW, evb, eWih, eWhh, ebih, ebhh,
                                                dWih, dWhh, dbih, dbhh, f1W, f1b, f2W, f2b,
                                                (const float4*)d_ws, out);
  }
}

// Round 2
// 1603.611 us; speedup vs baseline: 7.1825x; 7.1825x over previous
//
#include <hip/hip_runtime.h>
#include <math.h>

typedef _Float16 f16;
typedef _Float16 f16x8 __attribute__((ext_vector_type(8)));
typedef float    f32x4 __attribute__((ext_vector_type(4)));

#define NBLK 256
#define NTHR 512
#define MROW 64

// fragment regions in d_ws (units: 1 frag = 512 fp16 = 1KB; lane l holds 8 fp16 at l*8)
// B-frag content for v_mfma_f32_16x16x32_f16: lane l -> col j = jb + (l&15), k = kb + (l>>4)*8 + jj
#define DEC_F 0      // (jf<<5 | st<<3 | kc)           jf 0..15, st 0..3, kc 0..7
#define FC1_F 512    // 512 + jf*8 + kc
#define FC2_F 640    // 640 + kc
#define ENC_F 648    // 648 + jf*36 + (x: kc*3+st | h: 12 + kc*3+st)
#define TOT_F 1224
#define TOT_E (TOT_F*512)   // 626,688 fp16 = 1.25 MB

__device__ __forceinline__ float sigm(float v){
  v = fminf(fmaxf(v, -30.0f), 30.0f);
  return __fdividef(1.0f, 1.0f + __expf(-v));
}
__device__ __forceinline__ float tanh_f(float v){
  float t = fminf(fmaxf(v, -15.0f), 15.0f);
  float e = __expf(2.0f * t);
  return __fdividef(e - 1.0f, e + 1.0f);
}
// LDS element index with XOR swizzle (k bits [3:5] ^ row&7) — conflict-free b128 A reads
__device__ __forceinline__ int eH(int row, int k){ return row*256 + (k ^ ((row & 7) << 3)); }
__device__ __forceinline__ int eX(int row, int k){ return row*128 + (k ^ ((row & 7) << 3)); }

// ---------------- prep: pack all weights as fp16 B-fragments into d_ws ----------------
__global__ void prep_pack(const float* __restrict__ eWih, const float* __restrict__ eWhh,
                          const float* __restrict__ dWih, const float* __restrict__ dWhh,
                          const float* __restrict__ f1W,  const float* __restrict__ f2W,
                          f16* __restrict__ ws16)
{
  int idx = blockIdx.x * 256 + threadIdx.x;
  if (idx >= TOT_E) return;
  int frag = idx >> 9;
  int lo   = idx & 511;
  int l    = lo >> 3;
  int jj   = lo & 7;
  int c16  = l & 15;
  int q    = l >> 4;
  float v = 0.0f;
  if (frag < FC1_F){                       // decoder GRU
    int jf = frag >> 5, st = (frag >> 3) & 3, kc = frag & 7;
    int j = jf*16 + c16, k = kc*32 + q*8 + jj;
    if      (st == 0) v = dWih[j*256 + k]        + dWhh[j*256 + k];          // r (presummed)
    else if (st == 1) v = dWih[(256+j)*256 + k]  + dWhh[(256+j)*256 + k];    // z (presummed)
    else if (st == 2) v = dWih[(512+j)*256 + k];                             // in
    else              v = dWhh[(512+j)*256 + k];                             // hn
  } else if (frag < FC2_F){                // fc1
    int f = frag - FC1_F, jf = f >> 3, kc = f & 7;
    int j = jf*16 + c16, k = kc*32 + q*8 + jj;
    v = f1W[j*256 + k];
  } else if (frag < ENC_F){                // fc2 (cols >=2 zero-padded)
    int kc = frag - FC2_F;
    int j = c16, k = kc*32 + q*8 + jj;
    v = (j < 2) ? f2W[j*256 + k] : 0.0f;
  } else {                                 // encoder GRU
    int f = frag - ENC_F, jf = f / 36, r = f % 36;
    int j = jf*16 + c16;
    if (r < 12){ int kc = r/3, st = r%3; int k = kc*32 + q*8 + jj;
      v = eWih[(st*256 + j)*128 + k]; }
    else { r -= 12; int kc = r/3, st = r%3; int k = kc*32 + q*8 + jj;
      v = eWhh[(st*256 + j)*256 + k]; }
  }
  ws16[idx] = (f16)v;
}

// ---------------- fused persistent kernel ----------------
__global__ __launch_bounds__(NTHR, 2)
void fused_net(const float* __restrict__ x,
               const float* __restrict__ emW, const float* __restrict__ emb_,
               const float* __restrict__ evW, const float* __restrict__ evb,
               const float* __restrict__ ebih, const float* __restrict__ ebhh,
               const float* __restrict__ dbih, const float* __restrict__ dbhh,
               const float* __restrict__ f1b, const float* __restrict__ f2b,
               const f16* __restrict__ ws16, float* __restrict__ out)
{
  __shared__ __align__(16) f16 hb0[16384];   // [64][256] fp16, swizzled
  __shared__ __align__(16) f16 hb1[16384];
  __shared__ __align__(16) f16 xb[8192];     // [64][128] fp16, swizzled

  const int tid = threadIdx.x;
  const int r0  = blockIdx.x * MROW;
  const int l   = tid & 63;
  const int w   = tid >> 6;        // wave 0..7
  const int c16 = l & 15;
  const int q   = l >> 4;

  f16* hp = hb0;   // current h
  f16* hq = hb1;   // scratch / h_new

  for (int i = tid; i < 16384; i += NTHR) hb0[i] = (f16)0.0f;   // h0 = 0

  // hoisted per-lane biases (wave w owns col-frags 2w, 2w+1 for the whole kernel)
  float ebr[2], ebz[2], ebi[2], ebh[2];
  float dbr[2], dbz[2], dbi[2], dbh[2], f1bb[2];
  #pragma unroll
  for (int jfi = 0; jfi < 2; ++jfi){
    int j = (2*w + jfi)*16 + c16;
    ebr[jfi] = ebih[j]       + ebhh[j];
    ebz[jfi] = ebih[256 + j] + ebhh[256 + j];
    ebi[jfi] = ebih[512 + j];
    ebh[jfi] = ebhh[512 + j];
    dbr[jfi] = dbih[j]       + dbhh[j];
    dbz[jfi] = dbih[256 + j] + dbhh[256 + j];
    dbi[jfi] = dbih[512 + j];
    dbh[jfi] = dbhh[512 + j];
    f1bb[jfi] = f1b[j];
  }
  const float f2bb = (c16 < 2) ? f2b[c16] : 0.0f;
  __syncthreads();

  // =============== ENCODER: 9 GRU steps ===============
  #pragma unroll 1
  for (int t = 0; t < 9; ++t){
    { // xt = tanh(embedding) -> xb
      int e  = tid & 127;
      int rq = tid >> 7;                      // 0..3 -> rows rq*16..+15
      const float* Wp = (t < 8) ? (evW + e*6) : (emW + e*6);
      float bb = (t < 8) ? evb[e] : emb_[e];
      float w0 = Wp[0], w1 = Wp[1], w2 = Wp[2], w3 = Wp[3], w4 = Wp[4], w5 = Wp[5];
      int xo = (t < 8) ? (6 + t*6) : 0;
      #pragma unroll 1
      for (int rr = 0; rr < 16; ++rr){
        int row = rq*16 + rr;
        const float* xs = x + (size_t)(r0 + row)*54 + xo;
        float a = bb + xs[0]*w0 + xs[1]*w1 + xs[2]*w2 + xs[3]*w3 + xs[4]*w4 + xs[5]*w5;
        xb[eX(row, e)] = (f16)tanh_f(a);
      }
    }
    __syncthreads();

    #pragma unroll 1
    for (int jfi = 0; jfi < 2; ++jfi){
      const int jf = 2*w + jfi;
      const f16* wpe = ws16 + (size_t)(ENC_F + jf*36)*512 + l*8;
      f32x4 ar[4], az[4], an[4], ah[4];
      #pragma unroll
      for (int rf = 0; rf < 4; ++rf){ ar[rf] = 0.f; az[rf] = 0.f; an[rf] = 0.f; ah[rf] = 0.f; }

      #pragma unroll
      for (int kc = 0; kc < 4; ++kc){            // x-part, K=128
        f16x8 av[4];
        #pragma unroll
        for (int rf = 0; rf < 4; ++rf){
          int row = rf*16 + c16;
          av[rf] = *(const f16x8*)&xb[eX(row, kc*32 + q*8)];
        }
        f16x8 b0 = *(const f16x8*)(wpe + (kc*3 + 0)*512);
        f16x8 b1 = *(const f16x8*)(wpe + (kc*3 + 1)*512);
        f16x8 b2 = *(const f16x8*)(wpe + (kc*3 + 2)*512);
        #pragma unroll
        for (int rf = 0; rf < 4; ++rf){
          ar[rf] = __builtin_amdgcn_mfma_f32_16x16x32_f16(av[rf], b0, ar[rf], 0, 0, 0);
          az[rf] = __builtin_amdgcn_mfma_f32_16x16x32_f16(av[rf], b1, az[rf], 0, 0, 0);
          an[rf] = __builtin_amdgcn_mfma_f32_16x16x32_f16(av[rf], b2, an[rf], 0, 0, 0);
        }
      }
      #pragma unroll
      for (int kc = 0; kc < 8; ++kc){            // h-part, K=256
        f16x8 av[4];
        #pragma unroll
        for (int rf = 0; rf < 4; ++rf){
          int row = rf*16 + c16;
          av[rf] = *(const f16x8*)&hp[eH(row, kc*32 + q*8)];
        }
        f16x8 b0 = *(const f16x8*)(wpe + (12 + kc*3 + 0)*512);
        f16x8 b1 = *(const f16x8*)(wpe + (12 + kc*3 + 1)*512);
        f16x8 b2 = *(const f16x8*)(wpe + (12 + kc*3 + 2)*512);
        #pragma unroll
        for (int rf = 0; rf < 4; ++rf){
          ar[rf] = __builtin_amdgcn_mfma_f32_16x16x32_f16(av[rf], b0, ar[rf], 0, 0, 0);
          az[rf] = __builtin_amdgcn_mfma_f32_16x16x32_f16(av[rf], b1, az[rf], 0, 0, 0);
          ah[rf] = __builtin_amdgcn_mfma_f32_16x16x32_f16(av[rf], b2, ah[rf], 0, 0, 0);
        }
      }
      int j = jf*16 + c16;
      #pragma unroll
      for (int rf = 0; rf < 4; ++rf){
        #pragma unroll
        for (int r = 0; r < 4; ++r){
          int row = rf*16 + q*4 + r;
          float rv = sigm(ar[rf][r] + ebr[jfi]);
          float zv = sigm(az[rf][r] + ebz[jfi]);
          float nv = tanh_f(an[rf][r] + ebi[jfi] + rv*(ah[rf][r] + ebh[jfi]));
          float ho = (float)hp[eH(row, j)];
          hq[eH(row, j)] = (f16)((1.0f - zv)*nv + zv*ho);
        }
      }
    }
    __syncthreads();
    { f16* tmp = hp; hp = hq; hq = tmp; }
  }

  // =============== DECODER: 32 x (GRU + fc1 + fc2) ===============
  #pragma unroll 1
  for (int s = 0; s < 32; ++s){
    // ---- GRU: reads hp, writes h_new -> hq ----
    #pragma unroll 1
    for (int jfi = 0; jfi < 2; ++jfi){
      const int jf = 2*w + jfi;
      const f16* wpd = ws16 + (size_t)(jf*32)*512 + l*8;
      f32x4 ac[4][4];
      #pragma unroll
      for (int st = 0; st < 4; ++st)
        #pragma unroll
        for (int rf = 0; rf < 4; ++rf) ac[st][rf] = 0.f;

      #pragma unroll
      for (int kc = 0; kc < 8; ++kc){
        f16x8 av[4];
        #pragma unroll
        for (int rf = 0; rf < 4; ++rf){
          int row = rf*16 + c16;
          av[rf] = *(const f16x8*)&hp[eH(row, kc*32 + q*8)];
        }
        #pragma unroll
        for (int st = 0; st < 4; ++st){
          f16x8 bv = *(const f16x8*)(wpd + (st*8 + kc)*512);
          #pragma unroll
          for (int rf = 0; rf < 4; ++rf)
            ac[st][rf] = __builtin_amdgcn_mfma_f32_16x16x32_f16(av[rf], bv, ac[st][rf], 0, 0, 0);
        }
      }
      int j = jf*16 + c16;
      #pragma unroll
      for (int rf = 0; rf < 4; ++rf){
        #pragma unroll
        for (int r = 0; r < 4; ++r){
          int row = rf*16 + q*4 + r;
          float rv = sigm(ac[0][rf][r] + dbr[jfi]);
          float zv = sigm(ac[1][rf][r] + dbz[jfi]);
          float nv = tanh_f(ac[2][rf][r] + dbi[jfi] + rv*(ac[3][rf][r] + dbh[jfi]));
          float ho = (float)hp[eH(row, j)];
          hq[eH(row, j)] = (f16)((1.0f - zv)*nv + zv*ho);
        }
      }
    }
    __syncthreads();

    // ---- FC1: a = relu(h_new @ W1.T + b1), reads hq, writes a -> hp (h_old dead) ----
    #pragma unroll 1
    for (int jfi = 0; jfi < 2; ++jfi){
      const int jf = 2*w + jfi;
      const f16* wp1 = ws16 + (size_t)(FC1_F + jf*8)*512 + l*8;
      f32x4 a1[4];
      #pragma unroll
      for (int rf = 0; rf < 4; ++rf) a1[rf] = 0.f;
      #pragma unroll
      for (int kc = 0; kc < 8; ++kc){
        f16x8 bv = *(const f16x8*)(wp1 + kc*512);
        #pragma unroll
        for (int rf = 0; rf < 4; ++rf){
          int row = rf*16 + c16;
          f16x8 av = *(const f16x8*)&hq[eH(row, kc*32 + q*8)];
          a1[rf] = __builtin_amdgcn_mfma_f32_16x16x32_f16(av, bv, a1[rf], 0, 0, 0);
        }
      }
      int j = jf*16 + c16;
      #pragma unroll
      for (int rf = 0; rf < 4; ++rf){
        #pragma unroll
        for (int r = 0; r < 4; ++r){
          int row = rf*16 + q*4 + r;
          hp[eH(row, j)] = (f16)fmaxf(a1[rf][r] + f1bb[jfi], 0.0f);
        }
      }
    }
    __syncthreads();

    // ---- FC2 (waves 0-3, one row-frag each): y = tanh(a @ W2.T + b2) -> out ----
    if (w < 4){
      const f16* wp2 = ws16 + (size_t)FC2_F*512 + l*8;
      f32x4 a2 = 0.f;
      #pragma unroll
      for (int kc = 0; kc < 8; ++kc){
        int row = w*16 + c16;
        f16x8 av = *(const f16x8*)&hp[eH(row, kc*32 + q*8)];
        f16x8 bv = *(const f16x8*)(wp2 + kc*512);
        a2 = __builtin_amdgcn_mfma_f32_16x16x32_f16(av, bv, a2, 0, 0, 0);
      }
      if (c16 < 2){
        #pragma unroll
        for (int r = 0; r < 4; ++r){
          int row = w*16 + q*4 + r;
          out[((size_t)(r0 + row)*32 + s)*2 + c16] = tanh_f(a2[r] + f2bb);
        }
      }
    }
    __syncthreads();
    { f16* tmp = hp; hp = hq; hq = tmp; }
  }
}

extern "C" void kernel_launch(void* const* d_in, const int* in_sizes, int n_in,
                              void* d_out, int out_size, void* d_ws, size_t ws_size,
                              hipStream_t stream)
{
  (void)in_sizes; (void)n_in; (void)out_size; (void)ws_size;
  const float* x    = (const float*)d_in[0];
  const float* emW  = (const float*)d_in[1];
  const float* emb_ = (const float*)d_in[2];
  const float* evW  = (const float*)d_in[3];
  const float* evb  = (const float*)d_in[4];
  const float* eWih = (const float*)d_in[5];
  const float* eWhh = (const float*)d_in[6];
  const float* ebih = (const float*)d_in[7];
  const float* ebhh = (const float*)d_in[8];
  const float* dWih = (const float*)d_in[9];
  const float* dWhh = (const float*)d_in[10];
  const float* dbih = (const float*)d_in[11];
  const float* dbhh = (const float*)d_in[12];
  const float* f1W  = (const float*)d_in[13];
  const float* f1b  = (const float*)d_in[14];
  const float* f2W  = (const float*)d_in[15];
  const float* f2b  = (const float*)d_in[16];
  float* out = (float*)d_out;
  f16* ws16 = (f16*)d_ws;

  prep_pack<<<(TOT_E + 255)/256, 256, 0, stream>>>(eWih, eWhh, dWih, dWhh, f1W, f2W, ws16);
  fused_net<<<NBLK, NTHR, 0, stream>>>(x, emW, emb_, evW, evb, ebih, ebhh,
                                       dbih, dbhh, f1b, f2b, ws16, out);
}

// Round 3
// 1499.638 us; speedup vs baseline: 7.6805x; 1.0693x over previous
//
#include <hip/hip_runtime.h>
#include <math.h>

typedef _Float16 f16;
typedef _Float16 f16x8 __attribute__((ext_vector_type(8)));
typedef float    f32x4 __attribute__((ext_vector_type(4)));

#define NBLK 512
#define NTHR 512
#define MROW 32

// fragment regions in d_ws (1 frag = 512 fp16 = 1KB; lane l holds 8 fp16 at l*8)
// B-frag for v_mfma_f32_16x16x32_f16: lane l -> col j = jb + (l&15), k = kb + (l>>4)*8 + jj
#define DEC_F 0      // (jf<<5 | st<<3 | kc)           jf 0..15, st 0..3, kc 0..7
#define FC1_F 512    // 512 + jf*8 + kc
#define FC2_F 640    // 640 + kc
#define ENC_F 648    // 648 + jf*36 + (x: kc*3+st | h: 12 + kc*3+st)
#define TOT_F 1224
#define TOT_E (TOT_F*512)   // 626,688 fp16 = 1.25 MB

__device__ __forceinline__ float sigm(float v){
  // 1/(1+e^-v): saturates cleanly at both ends (1/inf -> 0), no clamp needed
  return __fdividef(1.0f, 1.0f + __expf(-v));
}
__device__ __forceinline__ float tanh_f(float v){
  float t = fminf(v, 8.0f);            // upper clamp only (avoids inf/inf NaN)
  float e = __expf(2.0f * t);
  return 1.0f - 2.0f * __fdividef(1.0f, e + 1.0f);
}
// LDS element index with XOR swizzle (k bits [3:5] ^ row&7) — conflict-light b128 A reads
__device__ __forceinline__ int eH(int row, int k){ return row*256 + (k ^ ((row & 7) << 3)); }
__device__ __forceinline__ int eX(int row, int k){ return row*128 + (k ^ ((row & 7) << 3)); }

// ---------------- prep: pack all weights as fp16 B-fragments into d_ws ----------------
__global__ void prep_pack(const float* __restrict__ eWih, const float* __restrict__ eWhh,
                          const float* __restrict__ dWih, const float* __restrict__ dWhh,
                          const float* __restrict__ f1W,  const float* __restrict__ f2W,
                          f16* __restrict__ ws16)
{
  int idx = blockIdx.x * 256 + threadIdx.x;
  if (idx >= TOT_E) return;
  int frag = idx >> 9;
  int lo   = idx & 511;
  int l    = lo >> 3;
  int jj   = lo & 7;
  int c16  = l & 15;
  int q    = l >> 4;
  float v = 0.0f;
  if (frag < FC1_F){                       // decoder GRU
    int jf = frag >> 5, st = (frag >> 3) & 3, kc = frag & 7;
    int j = jf*16 + c16, k = kc*32 + q*8 + jj;
    if      (st == 0) v = dWih[j*256 + k]        + dWhh[j*256 + k];          // r (presummed)
    else if (st == 1) v = dWih[(256+j)*256 + k]  + dWhh[(256+j)*256 + k];    // z (presummed)
    else if (st == 2) v = dWih[(512+j)*256 + k];                             // in
    else              v = dWhh[(512+j)*256 + k];                             // hn
  } else if (frag < FC2_F){                // fc1
    int f = frag - FC1_F, jf = f >> 3, kc = f & 7;
    int j = jf*16 + c16, k = kc*32 + q*8 + jj;
    v = f1W[j*256 + k];
  } else if (frag < ENC_F){                // fc2 (cols >=2 zero-padded)
    int kc = frag - FC2_F;
    int j = c16, k = kc*32 + q*8 + jj;
    v = (j < 2) ? f2W[j*256 + k] : 0.0f;
  } else {                                 // encoder GRU
    int f = frag - ENC_F, jf = f / 36, r = f % 36;
    int j = jf*16 + c16;
    if (r < 12){ int kc = r/3, st = r%3; int k = kc*32 + q*8 + jj;
      v = eWih[(st*256 + j)*128 + k]; }
    else { r -= 12; int kc = r/3, st = r%3; int k = kc*32 + q*8 + jj;
      v = eWhh[(st*256 + j)*256 + k]; }
  }
  ws16[idx] = (f16)v;
}

// ---------------- fused persistent kernel ----------------
__global__ __launch_bounds__(NTHR, 4)
void fused_net(const float* __restrict__ x,
               const float* __restrict__ emW, const float* __restrict__ emb_,
               const float* __restrict__ evW, const float* __restrict__ evb,
               const float* __restrict__ ebih, const float* __restrict__ ebhh,
               const float* __restrict__ dbih, const float* __restrict__ dbhh,
               const float* __restrict__ f1b, const float* __restrict__ f2b,
               const f16* __restrict__ ws16, float* __restrict__ out)
{
  __shared__ __align__(16) f16 hA[8192];   // [32][256] fp16, swizzled
  __shared__ __align__(16) f16 hB[8192];
  __shared__ __align__(16) f16 hC[8192];   // fc1-out (decoder); xb [32][128] (encoder)

  const int tid = threadIdx.x;
  const int r0  = blockIdx.x * MROW;
  const int l   = tid & 63;
  const int w   = tid >> 6;        // wave 0..7
  const int c16 = l & 15;
  const int q   = l >> 4;

  f16* hp = hA;
  f16* hq = hB;
  f16* xb = hC;

  for (int i = tid; i < 8192; i += NTHR) hA[i] = (f16)0.0f;   // h0 = 0

  // hoisted per-lane biases (wave w owns col-frags 2w, 2w+1 for the whole kernel)
  float ebr[2], ebz[2], ebi[2], ebh[2];
  float dbr[2], dbz[2], dbi[2], dbh[2], f1bb[2];
  #pragma unroll
  for (int jfi = 0; jfi < 2; ++jfi){
    int j = (2*w + jfi)*16 + c16;
    ebr[jfi] = ebih[j]       + ebhh[j];
    ebz[jfi] = ebih[256 + j] + ebhh[256 + j];
    ebi[jfi] = ebih[512 + j];
    ebh[jfi] = ebhh[512 + j];
    dbr[jfi] = dbih[j]       + dbhh[j];
    dbz[jfi] = dbih[256 + j] + dbhh[256 + j];
    dbi[jfi] = dbih[512 + j];
    dbh[jfi] = dbhh[512 + j];
    f1bb[jfi] = f1b[j];
  }
  const float f2bb = (c16 < 2) ? f2b[c16] : 0.0f;
  __syncthreads();

  // =============== ENCODER: 9 GRU steps ===============
  #pragma unroll 1
  for (int t = 0; t < 9; ++t){
    { // xt = tanh(embedding) -> xb (rows rq*8 .. rq*8+7)
      int e  = tid & 127;
      int rq = tid >> 7;                      // 0..3
      const float* Wp = (t < 8) ? (evW + e*6) : (emW + e*6);
      float bb = (t < 8) ? evb[e] : emb_[e];
      float w0 = Wp[0], w1 = Wp[1], w2 = Wp[2], w3 = Wp[3], w4 = Wp[4], w5 = Wp[5];
      int xo = (t < 8) ? (6 + t*6) : 0;
      #pragma unroll 1
      for (int rr = 0; rr < 8; ++rr){
        int row = rq*8 + rr;
        const float* xs = x + (size_t)(r0 + row)*54 + xo;
        float a = bb + xs[0]*w0 + xs[1]*w1 + xs[2]*w2 + xs[3]*w3 + xs[4]*w4 + xs[5]*w5;
        xb[eX(row, e)] = (f16)tanh_f(a);
      }
    }
    __syncthreads();

    #pragma unroll 1
    for (int jfi = 0; jfi < 2; ++jfi){
      const int jf = 2*w + jfi;
      const f16* wpe = ws16 + (size_t)(ENC_F + jf*36)*512 + l*8;
      f32x4 ar[2], az[2], an[2], ah[2];
      #pragma unroll
      for (int rf = 0; rf < 2; ++rf){ ar[rf] = 0.f; az[rf] = 0.f; an[rf] = 0.f; ah[rf] = 0.f; }

      #pragma unroll
      for (int kc = 0; kc < 4; ++kc){            // x-part, K=128
        f16x8 b0 = *(const f16x8*)(wpe + (kc*3 + 0)*512);
        f16x8 b1 = *(const f16x8*)(wpe + (kc*3 + 1)*512);
        f16x8 b2 = *(const f16x8*)(wpe + (kc*3 + 2)*512);
        f16x8 av[2];
        #pragma unroll
        for (int rf = 0; rf < 2; ++rf)
          av[rf] = *(const f16x8*)&xb[eX(rf*16 + c16, kc*32 + q*8)];
        #pragma unroll
        for (int rf = 0; rf < 2; ++rf){
          ar[rf] = __builtin_amdgcn_mfma_f32_16x16x32_f16(av[rf], b0, ar[rf], 0, 0, 0);
          az[rf] = __builtin_amdgcn_mfma_f32_16x16x32_f16(av[rf], b1, az[rf], 0, 0, 0);
          an[rf] = __builtin_amdgcn_mfma_f32_16x16x32_f16(av[rf], b2, an[rf], 0, 0, 0);
        }
      }
      #pragma unroll
      for (int kc = 0; kc < 8; ++kc){            // h-part, K=256
        f16x8 b0 = *(const f16x8*)(wpe + (12 + kc*3 + 0)*512);
        f16x8 b1 = *(const f16x8*)(wpe + (12 + kc*3 + 1)*512);
        f16x8 b2 = *(const f16x8*)(wpe + (12 + kc*3 + 2)*512);
        f16x8 av[2];
        #pragma unroll
        for (int rf = 0; rf < 2; ++rf)
          av[rf] = *(const f16x8*)&hp[eH(rf*16 + c16, kc*32 + q*8)];
        #pragma unroll
        for (int rf = 0; rf < 2; ++rf){
          ar[rf] = __builtin_amdgcn_mfma_f32_16x16x32_f16(av[rf], b0, ar[rf], 0, 0, 0);
          az[rf] = __builtin_amdgcn_mfma_f32_16x16x32_f16(av[rf], b1, az[rf], 0, 0, 0);
          ah[rf] = __builtin_amdgcn_mfma_f32_16x16x32_f16(av[rf], b2, ah[rf], 0, 0, 0);
        }
      }
      int j = jf*16 + c16;
      #pragma unroll
      for (int rf = 0; rf < 2; ++rf){
        #pragma unroll
        for (int r = 0; r < 4; ++r){
          int row = rf*16 + q*4 + r;
          float rv = sigm(ar[rf][r] + ebr[jfi]);
          float zv = sigm(az[rf][r] + ebz[jfi]);
          float nv = tanh_f(an[rf][r] + ebi[jfi] + rv*(ah[rf][r] + ebh[jfi]));
          float ho = (float)hp[eH(row, j)];
          hq[eH(row, j)] = (f16)(nv + zv*(ho - nv));
        }
      }
    }
    __syncthreads();
    { f16* tmp = hp; hp = hq; hq = tmp; }
  }

  // =============== DECODER: 32 x (GRU + fc1 + fc2) ===============
  // buffers: hp = h_in, hq = h_new (ping-pong), hC = fc1-out (fixed)
  #pragma unroll 1
  for (int s = 0; s < 32; ++s){
    // ---- GRU: reads hp, writes h_new -> hq ----
    #pragma unroll 1
    for (int jfi = 0; jfi < 2; ++jfi){
      const int jf = 2*w + jfi;
      const f16* wpd = ws16 + (size_t)(jf*32)*512 + l*8;
      f32x4 ac[4][2];
      #pragma unroll
      for (int st = 0; st < 4; ++st)
        #pragma unroll
        for (int rf = 0; rf < 2; ++rf) ac[st][rf] = 0.f;

      #pragma unroll
      for (int kc = 0; kc < 8; ++kc){
        f16x8 bv[4];
        #pragma unroll
        for (int st = 0; st < 4; ++st) bv[st] = *(const f16x8*)(wpd + (st*8 + kc)*512);
        f16x8 av[2];
        #pragma unroll
        for (int rf = 0; rf < 2; ++rf)
          av[rf] = *(const f16x8*)&hp[eH(rf*16 + c16, kc*32 + q*8)];
        #pragma unroll
        for (int st = 0; st < 4; ++st)
          #pragma unroll
          for (int rf = 0; rf < 2; ++rf)
            ac[st][rf] = __builtin_amdgcn_mfma_f32_16x16x32_f16(av[rf], bv[st], ac[st][rf], 0, 0, 0);
      }
      int j = jf*16 + c16;
      #pragma unroll
      for (int rf = 0; rf < 2; ++rf){
        #pragma unroll
        for (int r = 0; r < 4; ++r){
          int row = rf*16 + q*4 + r;
          float rv = sigm(ac[0][rf][r] + dbr[jfi]);
          float zv = sigm(ac[1][rf][r] + dbz[jfi]);
          float nv = tanh_f(ac[2][rf][r] + dbi[jfi] + rv*(ac[3][rf][r] + dbh[jfi]));
          float ho = (float)hp[eH(row, j)];
          hq[eH(row, j)] = (f16)(nv + zv*(ho - nv));
        }
      }
    }
    __syncthreads();

    // ---- FC1: a = relu(h_new @ W1.T + b1), reads hq, writes -> hC ----
    #pragma unroll 1
    for (int jfi = 0; jfi < 2; ++jfi){
      const int jf = 2*w + jfi;
      const f16* wp1 = ws16 + (size_t)(FC1_F + jf*8)*512 + l*8;
      f32x4 a1[2];
      #pragma unroll
      for (int rf = 0; rf < 2; ++rf) a1[rf] = 0.f;
      #pragma unroll
      for (int kc = 0; kc < 8; ++kc){
        f16x8 bv = *(const f16x8*)(wp1 + kc*512);
        #pragma unroll
        for (int rf = 0; rf < 2; ++rf){
          f16x8 av = *(const f16x8*)&hq[eH(rf*16 + c16, kc*32 + q*8)];
          a1[rf] = __builtin_amdgcn_mfma_f32_16x16x32_f16(av, bv, a1[rf], 0, 0, 0);
        }
      }
      int j = jf*16 + c16;
      #pragma unroll
      for (int rf = 0; rf < 2; ++rf)
        #pragma unroll
        for (int r = 0; r < 4; ++r){
          int row = rf*16 + q*4 + r;
          hC[eH(row, j)] = (f16)fmaxf(a1[rf][r] + f1bb[jfi], 0.0f);
        }
    }
    __syncthreads();

    // ---- FC2 (waves 0-1): y = tanh(hC @ W2.T + b2) -> out; overlaps next GRU on waves 2-7 ----
    if (w < 2){
      const f16* wp2 = ws16 + (size_t)FC2_F*512 + l*8;
      f32x4 a2 = 0.f;
      #pragma unroll
      for (int kc = 0; kc < 8; ++kc){
        f16x8 av = *(const f16x8*)&hC[eH(w*16 + c16, kc*32 + q*8)];
        f16x8 bv = *(const f16x8*)(wp2 + kc*512);
        a2 = __builtin_amdgcn_mfma_f32_16x16x32_f16(av, bv, a2, 0, 0, 0);
      }
      if (c16 < 2){
        #pragma unroll
        for (int r = 0; r < 4; ++r){
          int row = w*16 + q*4 + r;
          out[((size_t)(r0 + row)*32 + s)*2 + c16] = tanh_f(a2[r] + f2bb);
        }
      }
    }
    // no barrier here: next GRU reads hq / writes hp, FC2 reads hC — disjoint.
    { f16* tmp = hp; hp = hq; hq = tmp; }
  }
}

extern "C" void kernel_launch(void* const* d_in, const int* in_sizes, int n_in,
                              void* d_out, int out_size, void* d_ws, size_t ws_size,
                              hipStream_t stream)
{
  (void)in_sizes; (void)n_in; (void)out_size; (void)ws_size;
  const float* x    = (const float*)d_in[0];
  const float* emW  = (const float*)d_in[1];
  const float* emb_ = (const float*)d_in[2];
  const float* evW  = (const float*)d_in[3];
  const float* evb  = (const float*)d_in[4];
  const float* eWih = (const float*)d_in[5];
  const float* eWhh = (const float*)d_in[6];
  const float* ebih = (const float*)d_in[7];
  const float* ebhh = (const float*)d_in[8];
  const float* dWih = (const float*)d_in[9];
  const float* dWhh = (const float*)d_in[10];
  const float* dbih = (const float*)d_in[11];
  const float* dbhh = (const float*)d_in[12];
  const float* f1W  = (const float*)d_in[13];
  const float* f1b  = (const float*)d_in[14];
  const float* f2W  = (const float*)d_in[15];
  const float* f2b  = (const float*)d_in[16];
  float* out = (float*)d_out;
  f16* ws16 = (f16*)d_ws;

  prep_pack<<<(TOT_E + 255)/256, 256, 0, stream>>>(eWih, eWhh, dWih, dWhh, f1W, f2W, ws16);
  fused_net<<<NBLK, NTHR, 0, stream>>>(x, emW, emb_, evW, evb, ebih, ebhh,
                                       dbih, dbhh, f1b, f2b, ws16, out);
}